// Round 12
// baseline (315.227 us; speedup 1.0000x reference)
//
#include <hip/hip_runtime.h>
#include <math.h>

#define N_NODES 100000
#define N_EDGES 1600000
#define N_GRAPHS 512
#define HID 64
#define NC 3

#define NBUCK 782        // ceil(100000/128) buckets of 128 nodes
#define EPB 16384        // edges per block in partition
#define NPBLK 98         // ceil(1600000/16384)
#define PSTRIDE 3072     // part entries reserved per bucket (mean 2048, sigma 45)
#define BSTRIDE 4096     // col entries reserved per bucket
#define DUMMY N_NODES    // padded col entries point at a zeroed row
#define SRCMASK 0x1FFFF  // 17 bits: N_NODES < 131072
#define NFBLK 1563       // ceil(100000/64) fused-layer blocks (64 nodes each)

typedef unsigned int uint;

__device__ __forceinline__ ushort f2bf(float f) {
    uint u = __float_as_uint(f);
    u += 0x7fffu + ((u >> 16) & 1u);   // RNE
    return (ushort)(u >> 16);
}
__device__ __forceinline__ uint packbf2(float a, float b) {
    return (uint)f2bf(a) | ((uint)f2bf(b) << 16);
}

// ---------------- partition: edges -> fixed per-bucket regions, packed 4B entries ----------------
// entry = (dst&127)<<17 | src. 98 blocks x 1024 threads: long per-(block,bucket)
// runs minimize write-allocate line RFOs.

__global__ __launch_bounds__(1024) void partition_kernel(const int* __restrict__ src,
                                                         const int* __restrict__ dst,
                                                         int* __restrict__ ccursor,
                                                         uint* __restrict__ part) {
    __shared__ int cnt[NBUCK];
    __shared__ int base[NBUCK];
    __shared__ int cur[NBUCK];
    for (int i = threadIdx.x; i < NBUCK; i += 1024) { cnt[i] = 0; cur[i] = 0; }
    __syncthreads();
    const int4* d4 = (const int4*)dst;
    const int4* s4 = (const int4*)src;
    int i0 = blockIdx.x * (EPB / 4);
    int i1 = min(i0 + EPB / 4, N_EDGES / 4);
    for (int i = i0 + threadIdx.x; i < i1; i += 1024) {
        int4 d = d4[i];
        atomicAdd(&cnt[d.x >> 7], 1);
        atomicAdd(&cnt[d.y >> 7], 1);
        atomicAdd(&cnt[d.z >> 7], 1);
        atomicAdd(&cnt[d.w >> 7], 1);
    }
    __syncthreads();
    for (int i = threadIdx.x; i < NBUCK; i += 1024)
        base[i] = cnt[i] ? (i * PSTRIDE + atomicAdd(&ccursor[i], cnt[i])) : 0;
    __syncthreads();
    for (int i = i0 + threadIdx.x; i < i1; i += 1024) {
        int4 d = d4[i];
        int4 s = s4[i];
        int b0 = d.x >> 7; part[base[b0] + atomicAdd(&cur[b0], 1)] = ((uint)(d.x & 127) << 17) | (uint)s.x;
        int b1 = d.y >> 7; part[base[b1] + atomicAdd(&cur[b1], 1)] = ((uint)(d.y & 127) << 17) | (uint)s.y;
        int b2 = d.z >> 7; part[base[b2] + atomicAdd(&cur[b2], 1)] = ((uint)(d.z & 127) << 17) | (uint)s.z;
        int b3 = d.w >> 7; part[base[b3] + atomicAdd(&cur[b3], 1)] = ((uint)(d.w & 127) << 17) | (uint)s.w;
    }
}

// Per bucket: LDS histogram of its 128 nodes, padded-to-8 prefix scan, ranked
// placement into col[bucket*BSTRIDE ...], pad slots filled with DUMMY.

__global__ __launch_bounds__(256) void bcsr_kernel(const uint* __restrict__ part,
                                                   const int* __restrict__ ccursor,
                                                   int* __restrict__ row_ptr,
                                                   int* __restrict__ pdeg,
                                                   int* __restrict__ col) {
    __shared__ int deg[128];
    __shared__ int cur[128];
    __shared__ int pre[128];
    __shared__ int ss[256];
    int b = blockIdx.x;
    int t = threadIdx.x;
    int s0 = b * PSTRIDE;
    int s1 = s0 + ccursor[b];
    if (t < 128) { deg[t] = 0; cur[t] = 0; }
    __syncthreads();
    for (int e = s0 + t; e < s1; e += 256)
        atomicAdd(&deg[part[e] >> 17], 1);
    __syncthreads();
    int v = (t < 128) ? ((deg[t] + 7) & ~7) : 0;  // degree padded to 8
    int val = v;
    ss[t] = val;
    __syncthreads();
    for (int off = 1; off < 256; off <<= 1) {
        int o = (t >= off) ? ss[t - off] : 0;
        __syncthreads();
        val += o;
        ss[t] = val;
        __syncthreads();
    }
    if (t < 128) pre[t] = val - v;
    __syncthreads();
    int base = b * BSTRIDE;
    int node = b * 128 + t;
    if (t < 128 && node < N_NODES) {
        row_ptr[node] = base + pre[t];
        pdeg[node] = v;
    }
    for (int e = s0 + t; e < s1; e += 256) {
        uint p = part[e];
        int nl = p >> 17;
        int r = atomicAdd(&cur[nl], 1);
        col[base + pre[nl] + r] = (int)(p & SRCMASK);
    }
    __syncthreads();
    if (t < 128) {
        for (int i = deg[t]; i < v; i++)
            col[base + pre[t] + i] = DUMMY;
    }
}

// ---------------- prep: x->bf16, W->bf16 transposed, zero dummy row + pads ----------------

__global__ __launch_bounds__(256) void cvt_kernel(const float* __restrict__ x,
                                                  ushort* __restrict__ hX,
                                                  ushort* __restrict__ hA,
                                                  ushort* __restrict__ hB,
                                                  const float* __restrict__ W_rel,
                                                  const float* __restrict__ W_root,
                                                  ushort* __restrict__ WT,
                                                  int* __restrict__ row_ptr,
                                                  int* __restrict__ pdeg) {
    int gid = blockIdx.x * blockDim.x + threadIdx.x;
    int stride = gridDim.x * blockDim.x;
    if (gid < HID) {   // zero DUMMY row of each h buffer
        hX[(size_t)N_NODES * HID + gid] = 0;
        hA[(size_t)N_NODES * HID + gid] = 0;
        hB[(size_t)N_NODES * HID + gid] = 0;
    }
    if (gid < 64) {    // neutral CSR entries for padding nodes N_NODES..N_NODES+63
        pdeg[N_NODES + gid] = 0;
        row_ptr[N_NODES + gid] = 0;
    }
    const float4* x4 = (const float4*)x;
    for (int i = gid; i < N_NODES * HID / 4; i += stride) {
        float4 v = x4[i];
        uint2 o;
        o.x = packbf2(v.x, v.y);
        o.y = packbf2(v.z, v.w);
        *(uint2*)(hX + (size_t)i * 4) = o;
    }
    for (int i = gid; i < NC * 2 * HID * HID; i += stride) {
        int l = i / (2 * HID * HID);
        int rem = i % (2 * HID * HID);
        int m = rem / (HID * HID);
        int j = rem % (HID * HID);
        int colc = j / HID;
        int k = j % HID;
        const float* W = (m ? W_root : W_rel) + l * HID * HID;
        WT[i] = f2bf(W[k * HID + colc]);
    }
}

// ---------------- fused layer: hout = relu(gather(hin)@Wrel + hin@Wroot + b) ----------------
// Block = 4 waves x 64 nodes (wave-private 16). Gather: 4 passes x 4-node slots,
// 8-deep load pipeline, fp32 acc -> bf16 into wave-private LDS. Transform: MFMA
// with agg A-frags from LDS, h from global, W hoisted in regs. Epilogue restages
// bf16 rows through the same LDS for coalesced 32B stores. DS ops are per-wave
// in-order => NO __syncthreads anywhere (zero inter-wave coupling).

#define ACC4(A, v) { A.x += __uint_as_float((v).x << 16); \
                     A.y += __uint_as_float((v).x & 0xffff0000u); \
                     A.z += __uint_as_float((v).y << 16); \
                     A.w += __uint_as_float((v).y & 0xffff0000u); }

__global__ __launch_bounds__(256) void layer_kernel(
    const ushort* __restrict__ hin, ushort* __restrict__ hout,
    const int* __restrict__ row_ptr, const int* __restrict__ pdeg,
    const int* __restrict__ col, const ushort* __restrict__ WTl,
    const float* __restrict__ bias)
{
    typedef __attribute__((ext_vector_type(8))) short short8;
    typedef __attribute__((ext_vector_type(4))) float f32x4;
    __shared__ ushort sagg[4][16][80];   // [wave][node][ch], 160B rows (16B-aligned)
    int lane = threadIdx.x & 63;
    int w = threadIdx.x >> 6;
    int nbase = blockIdx.x * 64 + w * 16;

    // ---- gather phase ----
    int slot = lane >> 4;
    int ch = (lane & 15) * 4;
#pragma unroll
    for (int p = 0; p < 4; p++) {
        int nl = p * 4 + slot;
        int n = nbase + nl;
        const int* row = col + row_ptr[n];
        int pd = pdeg[n];
        float4 a0 = {0.f,0.f,0.f,0.f}, a1 = {0.f,0.f,0.f,0.f};
        float4 a2 = {0.f,0.f,0.f,0.f}, a3 = {0.f,0.f,0.f,0.f};
        for (int e = 0; e < pd; e += 8) {
            int4 ca = *(const int4*)(row + e);
            int4 cb = *(const int4*)(row + e + 4);
            uint2 v0 = *(const uint2*)(hin + (size_t)ca.x * HID + ch);
            uint2 v1 = *(const uint2*)(hin + (size_t)ca.y * HID + ch);
            uint2 v2 = *(const uint2*)(hin + (size_t)ca.z * HID + ch);
            uint2 v3 = *(const uint2*)(hin + (size_t)ca.w * HID + ch);
            uint2 v4 = *(const uint2*)(hin + (size_t)cb.x * HID + ch);
            uint2 v5 = *(const uint2*)(hin + (size_t)cb.y * HID + ch);
            uint2 v6 = *(const uint2*)(hin + (size_t)cb.z * HID + ch);
            uint2 v7 = *(const uint2*)(hin + (size_t)cb.w * HID + ch);
            ACC4(a0, v0); ACC4(a1, v1); ACC4(a2, v2); ACC4(a3, v3);
            ACC4(a0, v4); ACC4(a1, v5); ACC4(a2, v6); ACC4(a3, v7);
        }
        a0.x += a1.x + a2.x + a3.x;
        a0.y += a1.y + a2.y + a3.y;
        a0.z += a1.z + a2.z + a3.z;
        a0.w += a1.w + a2.w + a3.w;
        uint2 o;
        o.x = packbf2(a0.x, a0.y);
        o.y = packbf2(a0.z, a0.w);
        *(uint2*)&sagg[w][nl][ch] = o;
    }

    // ---- transform phase (wave-private; DS in-order guarantees agg visibility) ----
    int mrow = lane & 15;
    int kg = lane >> 4;
    short8 Bf[4][4];   // [col-tile][rel_h0, rel_h1, root_h0, root_h1]
#pragma unroll
    for (int c = 0; c < 4; c++)
#pragma unroll
        for (int m = 0; m < 2; m++)
#pragma unroll
            for (int h = 0; h < 2; h++)
                Bf[c][m * 2 + h] = *(const short8*)(
                    WTl + m * HID * HID + (c * 16 + mrow) * HID + h * 32 + kg * 8);
    float bv[4];
#pragma unroll
    for (int c = 0; c < 4; c++) bv[c] = bias[c * 16 + mrow];

    int n = nbase + mrow;
    size_t rb = (size_t)n * HID + kg * 8;
    short8 Ah0 = *(const short8*)(hin + rb);
    short8 Ah1 = *(const short8*)(hin + rb + 32);
    short8 Aa0 = *(const short8*)&sagg[w][mrow][kg * 8];
    short8 Aa1 = *(const short8*)&sagg[w][mrow][32 + kg * 8];

#pragma unroll
    for (int c = 0; c < 4; c++) {
        f32x4 acc = {0.f, 0.f, 0.f, 0.f};
        acc = __builtin_amdgcn_mfma_f32_16x16x32_bf16(Aa0, Bf[c][0], acc, 0, 0, 0);
        acc = __builtin_amdgcn_mfma_f32_16x16x32_bf16(Aa1, Bf[c][1], acc, 0, 0, 0);
        acc = __builtin_amdgcn_mfma_f32_16x16x32_bf16(Ah0, Bf[c][2], acc, 0, 0, 0);
        acc = __builtin_amdgcn_mfma_f32_16x16x32_bf16(Ah1, Bf[c][3], acc, 0, 0, 0);
        // restage as bf16 into the (now-consumed) wave-private LDS
#pragma unroll
        for (int r = 0; r < 4; r++)
            sagg[w][kg * 4 + r][c * 16 + mrow] = f2bf(fmaxf(acc[r] + bv[c], 0.f));
    }

    if (n < N_NODES) {
        uint4 o0 = *(const uint4*)&sagg[w][mrow][kg * 16];
        uint4 o1 = *(const uint4*)&sagg[w][mrow][kg * 16 + 8];
        ushort* orow = hout + (size_t)n * HID + kg * 16;
        *(uint4*)(orow) = o0;
        *(uint4*)(orow + 8) = o1;
    }
}

// ---------------- pooling (batch sorted, bf16 h): wave per 64-node chunk ----------------

__global__ __launch_bounds__(256) void pool_kernel(
    const ushort* __restrict__ h, const int* __restrict__ batch,
    float* __restrict__ pooled_ws) {
    const int CH = 64;
    int lane = threadIdx.x & 63;
    int gwid = (blockIdx.x * blockDim.x + threadIdx.x) >> 6;
    int n0 = gwid * CH;
    if (n0 >= N_NODES) return;
    int nend = min(n0 + CH, N_NODES);
    int cur = batch[n0];
    float acc = 0.f;
    for (int n = n0; n < nend; n++) {
        int g = batch[n];
        if (g != cur) {
            atomicAdd(&pooled_ws[cur * HID + lane], acc);
            acc = 0.f;
            cur = g;
        }
        acc += __uint_as_float(((uint)h[(size_t)n * HID + lane]) << 16);
    }
    atomicAdd(&pooled_ws[cur * HID + lane], acc);
}

// ---------------- MLP readout (fp32, also copies pooled -> d_out) ----------------

__global__ void mlp_kernel(const float* __restrict__ pooled_ws,
                           const float* __restrict__ W1, const float* __restrict__ b1,
                           const float* __restrict__ W2, const float* __restrict__ b2,
                           float* __restrict__ out, float* __restrict__ pooled_out) {
    __shared__ float sp[HID];
    __shared__ float red[4];
    int g = blockIdx.x, t = threadIdx.x;
    if (t < HID) {
        float v = pooled_ws[g * HID + t];
        sp[t] = v;
        pooled_out[g * HID + t] = v;
    }
    __syncthreads();
    float acc = b1[t];
#pragma unroll
    for (int k = 0; k < HID; k++) acc = fmaf(sp[k], W1[k * 128 + t], acc);
    float hid = fmaxf(acc, 0.f);
    float p0 = hid * W2[t * 2 + 0];
    float p1 = hid * W2[t * 2 + 1];
    for (int off = 32; off > 0; off >>= 1) {
        p0 += __shfl_down(p0, off, 64);
        p1 += __shfl_down(p1, off, 64);
    }
    int wave = t >> 6, lane = t & 63;
    if (lane == 0) { red[wave * 2 + 0] = p0; red[wave * 2 + 1] = p1; }
    __syncthreads();
    if (t == 0) {
        float o0 = red[0] + red[2] + b2[0];
        float o1 = red[1] + red[3] + b2[1];
        out[g * 2 + 0] = 1.f / (1.f + expf(-o0));
        out[g * 2 + 1] = 1.f / (1.f + expf(-o1));
    }
}

// ---------------- launcher ----------------

extern "C" void kernel_launch(void* const* d_in, const int* in_sizes, int n_in,
                              void* d_out, int out_size, void* d_ws, size_t ws_size,
                              hipStream_t stream) {
    const float* x      = (const float*)d_in[0];
    const int*   ei     = (const int*)d_in[1];
    const int*   batch  = (const int*)d_in[2];
    const float* W_rel  = (const float*)d_in[3];
    const float* W_root = (const float*)d_in[4];
    const float* b_conv = (const float*)d_in[5];
    const float* W1     = (const float*)d_in[6];
    const float* b1     = (const float*)d_in[7];
    const float* W2     = (const float*)d_in[8];
    const float* b2     = (const float*)d_in[9];

    float* outp       = (float*)d_out;                 // [512,2]
    float* pooled_out = (float*)d_out + N_GRAPHS * 2;  // [512,64]

    // h buffers: N_NODES + DUMMY + 63 padding rows (padding reads are discarded)
    const size_t HROWS_B = ((size_t)(N_NODES + 64) * HID * 2 + 255) & ~(size_t)255;

    char* ws = (char*)d_ws;
    size_t off = 0;
    ushort* hX = (ushort*)(ws + off); off += HROWS_B;
    ushort* hA = (ushort*)(ws + off); off += HROWS_B;
    ushort* hB = (ushort*)(ws + off); off += HROWS_B;
    ushort* WT = (ushort*)(ws + off); off += ((size_t)NC * 2 * HID * HID * 2 + 255) & ~(size_t)255;
    uint* part    = (uint*)(ws + off); off += (size_t)NBUCK * PSTRIDE * 4;
    int* colidx   = (int*)(ws + off); off += (size_t)NBUCK * BSTRIDE * 4;
    int* row_ptr  = (int*)(ws + off); off += (size_t)(N_NODES + 68) * 4;
    int* pdeg     = (int*)(ws + off); off += (size_t)(N_NODES + 68) * 4;
    int* ccursor  = (int*)(ws + off); off += (size_t)NBUCK * 4;
    float* pooled_ws = (float*)(ws + off); off += (size_t)N_GRAPHS * HID * 4;

    const int* esrc = ei;
    const int* edst = ei + N_EDGES;

    hipMemsetAsync(ccursor, 0, (size_t)NBUCK * 4, stream);
    hipMemsetAsync(pooled_ws, 0, (size_t)N_GRAPHS * HID * 4, stream);

    cvt_kernel<<<2048, 256, 0, stream>>>(x, hX, hA, hB, W_rel, W_root, WT, row_ptr, pdeg);

    partition_kernel<<<NPBLK, 1024, 0, stream>>>(esrc, edst, ccursor, part);
    bcsr_kernel<<<NBUCK, 256, 0, stream>>>(part, ccursor, row_ptr, pdeg, colidx);

    layer_kernel<<<NFBLK, 256, 0, stream>>>(hX, hA, row_ptr, pdeg, colidx,
                                            WT + 0 * 2 * HID * HID, b_conv + 0 * HID);
    layer_kernel<<<NFBLK, 256, 0, stream>>>(hA, hB, row_ptr, pdeg, colidx,
                                            WT + 1 * 2 * HID * HID, b_conv + 1 * HID);
    layer_kernel<<<NFBLK, 256, 0, stream>>>(hB, hA, row_ptr, pdeg, colidx,
                                            WT + 2 * 2 * HID * HID, b_conv + 2 * HID);

    pool_kernel<<<391, 256, 0, stream>>>(hA, batch, pooled_ws);
    mlp_kernel<<<N_GRAPHS, 128, 0, stream>>>(pooled_ws, W1, b1, W2, b2, outp, pooled_out);
}

// Round 13
// 279.972 us; speedup vs baseline: 1.1259x; 1.1259x over previous
//
#include <hip/hip_runtime.h>
#include <math.h>

#define N_NODES 100000
#define N_EDGES 1600000
#define N_GRAPHS 512
#define HID 64
#define NC 3

#define NBUCK 782        // ceil(100000/128) buckets of 128 nodes
#define EPB 8192         // edges per block in partition
#define NPBLK 196        // ceil(1600000/8192)
#define PSTRIDE 3072     // part entries reserved per bucket (mean 2048, sigma 45)
#define BSTRIDE 4096     // col entries reserved per bucket
#define DUMMY N_NODES    // padded col entries point at a zeroed row
#define SRCMASK 0x1FFFF  // 17 bits: N_NODES < 131072

typedef unsigned int uint;

__device__ __forceinline__ ushort f2bf(float f) {
    uint u = __float_as_uint(f);
    u += 0x7fffu + ((u >> 16) & 1u);   // RNE
    return (ushort)(u >> 16);
}
__device__ __forceinline__ uint packbf2(float a, float b) {
    return (uint)f2bf(a) | ((uint)f2bf(b) << 16);
}

// ---------------- partition: edges -> fixed per-bucket regions, packed 4B entries ----------------
// entry = (dst&127)<<17 | src. 196 blocks x 512 threads (R11 measured config).

__global__ __launch_bounds__(512) void partition_kernel(const int* __restrict__ src,
                                                        const int* __restrict__ dst,
                                                        int* __restrict__ ccursor,
                                                        uint* __restrict__ part) {
    __shared__ int cnt[NBUCK];
    __shared__ int base[NBUCK];
    __shared__ int cur[NBUCK];
    for (int i = threadIdx.x; i < NBUCK; i += 512) { cnt[i] = 0; cur[i] = 0; }
    __syncthreads();
    const int4* d4 = (const int4*)dst;
    const int4* s4 = (const int4*)src;
    int i0 = blockIdx.x * (EPB / 4);
    int i1 = min(i0 + EPB / 4, N_EDGES / 4);
    for (int i = i0 + threadIdx.x; i < i1; i += 512) {
        int4 d = d4[i];
        atomicAdd(&cnt[d.x >> 7], 1);
        atomicAdd(&cnt[d.y >> 7], 1);
        atomicAdd(&cnt[d.z >> 7], 1);
        atomicAdd(&cnt[d.w >> 7], 1);
    }
    __syncthreads();
    for (int i = threadIdx.x; i < NBUCK; i += 512)
        base[i] = cnt[i] ? (i * PSTRIDE + atomicAdd(&ccursor[i], cnt[i])) : 0;
    __syncthreads();
    for (int i = i0 + threadIdx.x; i < i1; i += 512) {
        int4 d = d4[i];
        int4 s = s4[i];
        int b0 = d.x >> 7; part[base[b0] + atomicAdd(&cur[b0], 1)] = ((uint)(d.x & 127) << 17) | (uint)s.x;
        int b1 = d.y >> 7; part[base[b1] + atomicAdd(&cur[b1], 1)] = ((uint)(d.y & 127) << 17) | (uint)s.y;
        int b2 = d.z >> 7; part[base[b2] + atomicAdd(&cur[b2], 1)] = ((uint)(d.z & 127) << 17) | (uint)s.z;
        int b3 = d.w >> 7; part[base[b3] + atomicAdd(&cur[b3], 1)] = ((uint)(d.w & 127) << 17) | (uint)s.w;
    }
}

// Per bucket: LDS histogram of its 128 nodes, padded-to-8 prefix scan, ranked
// placement into col[bucket*BSTRIDE ...], pad slots filled with DUMMY.

__global__ __launch_bounds__(256) void bcsr_kernel(const uint* __restrict__ part,
                                                   const int* __restrict__ ccursor,
                                                   int* __restrict__ row_ptr,
                                                   int* __restrict__ pdeg,
                                                   int* __restrict__ col) {
    __shared__ int deg[128];
    __shared__ int cur[128];
    __shared__ int pre[128];
    __shared__ int ss[256];
    int b = blockIdx.x;
    int t = threadIdx.x;
    int s0 = b * PSTRIDE;
    int s1 = s0 + ccursor[b];
    if (t < 128) { deg[t] = 0; cur[t] = 0; }
    __syncthreads();
    for (int e = s0 + t; e < s1; e += 256)
        atomicAdd(&deg[part[e] >> 17], 1);
    __syncthreads();
    int v = (t < 128) ? ((deg[t] + 7) & ~7) : 0;  // degree padded to 8
    int val = v;
    ss[t] = val;
    __syncthreads();
    for (int off = 1; off < 256; off <<= 1) {
        int o = (t >= off) ? ss[t - off] : 0;
        __syncthreads();
        val += o;
        ss[t] = val;
        __syncthreads();
    }
    if (t < 128) pre[t] = val - v;
    __syncthreads();
    int base = b * BSTRIDE;
    int node = b * 128 + t;
    if (t < 128 && node < N_NODES) {
        row_ptr[node] = base + pre[t];
        pdeg[node] = v;
    }
    for (int e = s0 + t; e < s1; e += 256) {
        uint p = part[e];
        int nl = p >> 17;
        int r = atomicAdd(&cur[nl], 1);
        col[base + pre[nl] + r] = (int)(p & SRCMASK);
    }
    __syncthreads();
    if (t < 128) {
        for (int i = deg[t]; i < v; i++)
            col[base + pre[t] + i] = DUMMY;
    }
}

// ---------------- prep: x->bf16, W->bf16 transposed, zero dummy rows + ccursor + pooled ----------------

__global__ __launch_bounds__(256) void cvt_kernel(const float* __restrict__ x,
                                                  ushort* __restrict__ hX,
                                                  ushort* __restrict__ hA,
                                                  ushort* __restrict__ hB,
                                                  const float* __restrict__ W_rel,
                                                  const float* __restrict__ W_root,
                                                  ushort* __restrict__ WT,
                                                  int* __restrict__ ccursor,
                                                  float* __restrict__ pooled_ws) {
    int gid = blockIdx.x * blockDim.x + threadIdx.x;
    int stride = gridDim.x * blockDim.x;
    if (gid < HID) {   // zero DUMMY row of each h buffer
        hX[(size_t)N_NODES * HID + gid] = 0;
        hA[(size_t)N_NODES * HID + gid] = 0;
        hB[(size_t)N_NODES * HID + gid] = 0;
    }
    if (gid < NBUCK) ccursor[gid] = 0;
    if (gid < N_GRAPHS * HID) pooled_ws[gid] = 0.f;
    const float4* x4 = (const float4*)x;
    for (int i = gid; i < N_NODES * HID / 4; i += stride) {
        float4 v = x4[i];
        uint2 o;
        o.x = packbf2(v.x, v.y);
        o.y = packbf2(v.z, v.w);
        *(uint2*)(hX + (size_t)i * 4) = o;
    }
    for (int i = gid; i < NC * 2 * HID * HID; i += stride) {
        int l = i / (2 * HID * HID);
        int rem = i % (2 * HID * HID);
        int m = rem / (HID * HID);
        int j = rem % (HID * HID);
        int colc = j / HID;
        int k = j % HID;
        const float* W = (m ? W_root : W_rel) + l * HID * HID;
        WT[i] = f2bf(W[k * HID + colc]);
    }
}

// ---------------- gather (bf16 rows): agg[n] = sum hin[col[e]] ----------------
// Wave = 4 nodes x 16 lanes; lane covers 4 bf16 channels (8B). Rows padded to
// multiple of 8 -> unconditional 8-deep pipeline. fp32 accumulate, bf16 out.

#define ACC4(A, v) { A.x += __uint_as_float((v).x << 16); \
                     A.y += __uint_as_float((v).x & 0xffff0000u); \
                     A.z += __uint_as_float((v).y << 16); \
                     A.w += __uint_as_float((v).y & 0xffff0000u); }

__global__ __launch_bounds__(256) void gather_kernel(
    const ushort* __restrict__ hin, ushort* __restrict__ agg,
    const int* __restrict__ row_ptr, const int* __restrict__ pdeg,
    const int* __restrict__ col)
{
    int lane = threadIdx.x & 63;
    int slot = lane >> 4;
    int ch   = (lane & 15) * 4;
    int gwid = (blockIdx.x * blockDim.x + threadIdx.x) >> 6;
    int nwaves = (gridDim.x * blockDim.x) >> 6;

    for (int n0 = gwid * 4; n0 < N_NODES; n0 += nwaves * 4) {
        int n = n0 + slot;
        const int* row = col + row_ptr[n];
        int pd = pdeg[n];
        float4 a0 = {0.f,0.f,0.f,0.f}, a1 = {0.f,0.f,0.f,0.f};
        float4 a2 = {0.f,0.f,0.f,0.f}, a3 = {0.f,0.f,0.f,0.f};
        for (int e = 0; e < pd; e += 8) {
            int4 ca = *(const int4*)(row + e);
            int4 cb = *(const int4*)(row + e + 4);
            uint2 v0 = *(const uint2*)(hin + (size_t)ca.x * HID + ch);
            uint2 v1 = *(const uint2*)(hin + (size_t)ca.y * HID + ch);
            uint2 v2 = *(const uint2*)(hin + (size_t)ca.z * HID + ch);
            uint2 v3 = *(const uint2*)(hin + (size_t)ca.w * HID + ch);
            uint2 v4 = *(const uint2*)(hin + (size_t)cb.x * HID + ch);
            uint2 v5 = *(const uint2*)(hin + (size_t)cb.y * HID + ch);
            uint2 v6 = *(const uint2*)(hin + (size_t)cb.z * HID + ch);
            uint2 v7 = *(const uint2*)(hin + (size_t)cb.w * HID + ch);
            ACC4(a0, v0); ACC4(a1, v1); ACC4(a2, v2); ACC4(a3, v3);
            ACC4(a0, v4); ACC4(a1, v5); ACC4(a2, v6); ACC4(a3, v7);
        }
        a0.x += a1.x + a2.x + a3.x;
        a0.y += a1.y + a2.y + a3.y;
        a0.z += a1.z + a2.z + a3.z;
        a0.w += a1.w + a2.w + a3.w;
        uint2 o;
        o.x = packbf2(a0.x, a0.y);
        o.y = packbf2(a0.z, a0.w);
        *(uint2*)(agg + (size_t)n * HID + ch) = o;
    }
}

// ---------------- transform via MFMA: hout = relu(agg@Wrel + h@Wroot + b) ----------------
// Wave = 16 nodes x 64 out-ch. A frags from h/agg rows (lane&15 = node,
// lane>>4 = k-group of 8). B frags from WT (hoisted, loaded once).
// Epilogue through padded LDS for coalesced bf16 row stores.

__global__ __launch_bounds__(256) void transform_kernel(
    const ushort* __restrict__ hin, const ushort* __restrict__ agg,
    ushort* __restrict__ hout, const ushort* __restrict__ WTl,
    const float* __restrict__ bias)
{
    typedef __attribute__((ext_vector_type(8))) short short8;
    typedef __attribute__((ext_vector_type(4))) float f32x4;
    __shared__ float lds[4][16][68];
    int lane = threadIdx.x & 63;
    int wid  = threadIdx.x >> 6;
    int mrow = lane & 15;
    int kg   = lane >> 4;
    int gw = (blockIdx.x * blockDim.x + threadIdx.x) >> 6;
    int nw = (gridDim.x * blockDim.x) >> 6;

    short8 Bf[4][4];   // [col-tile][rel_h0, rel_h1, root_h0, root_h1]
#pragma unroll
    for (int c = 0; c < 4; c++)
#pragma unroll
        for (int m = 0; m < 2; m++)
#pragma unroll
            for (int h = 0; h < 2; h++)
                Bf[c][m * 2 + h] = *(const short8*)(
                    WTl + m * HID * HID + (c * 16 + mrow) * HID + h * 32 + kg * 8);

    float bv[4];
#pragma unroll
    for (int c = 0; c < 4; c++) bv[c] = bias[c * 16 + mrow];

    for (int ng = gw; ng < N_NODES / 16; ng += nw) {
        size_t rb = ((size_t)ng * 16 + mrow) * HID + kg * 8;
        short8 Ah0 = *(const short8*)(hin + rb);
        short8 Ah1 = *(const short8*)(hin + rb + 32);
        short8 Aa0 = *(const short8*)(agg + rb);
        short8 Aa1 = *(const short8*)(agg + rb + 32);
#pragma unroll
        for (int c = 0; c < 4; c++) {
            f32x4 acc = {0.f, 0.f, 0.f, 0.f};
            acc = __builtin_amdgcn_mfma_f32_16x16x32_bf16(Aa0, Bf[c][0], acc, 0, 0, 0);
            acc = __builtin_amdgcn_mfma_f32_16x16x32_bf16(Aa1, Bf[c][1], acc, 0, 0, 0);
            acc = __builtin_amdgcn_mfma_f32_16x16x32_bf16(Ah0, Bf[c][2], acc, 0, 0, 0);
            acc = __builtin_amdgcn_mfma_f32_16x16x32_bf16(Ah1, Bf[c][3], acc, 0, 0, 0);
#pragma unroll
            for (int r = 0; r < 4; r++)
                lds[wid][kg * 4 + r][c * 16 + mrow] = fmaxf(acc[r] + bv[c], 0.f);
        }
        asm volatile("s_waitcnt lgkmcnt(0)" ::: "memory");
        const float* lr = &lds[wid][mrow][kg * 16];
        float4 f0 = *(const float4*)(lr + 0);
        float4 f1 = *(const float4*)(lr + 4);
        float4 f2 = *(const float4*)(lr + 8);
        float4 f3 = *(const float4*)(lr + 12);
        uint4 o0, o1;
        o0.x = packbf2(f0.x, f0.y); o0.y = packbf2(f0.z, f0.w);
        o0.z = packbf2(f1.x, f1.y); o0.w = packbf2(f1.z, f1.w);
        o1.x = packbf2(f2.x, f2.y); o1.y = packbf2(f2.z, f2.w);
        o1.z = packbf2(f3.x, f3.y); o1.w = packbf2(f3.z, f3.w);
        ushort* orow = hout + ((size_t)ng * 16 + mrow) * HID + kg * 16;
        *(uint4*)(orow) = o0;
        *(uint4*)(orow + 8) = o1;
    }
}

// ---------------- pooling (batch sorted, bf16 h): wave per 64-node chunk ----------------

__global__ __launch_bounds__(256) void pool_kernel(
    const ushort* __restrict__ h, const int* __restrict__ batch,
    float* __restrict__ pooled_ws) {
    const int CH = 64;
    int lane = threadIdx.x & 63;
    int gwid = (blockIdx.x * blockDim.x + threadIdx.x) >> 6;
    int n0 = gwid * CH;
    if (n0 >= N_NODES) return;
    int nend = min(n0 + CH, N_NODES);
    int cur = batch[n0];
    float acc = 0.f;
    for (int n = n0; n < nend; n++) {
        int g = batch[n];
        if (g != cur) {
            atomicAdd(&pooled_ws[cur * HID + lane], acc);
            acc = 0.f;
            cur = g;
        }
        acc += __uint_as_float(((uint)h[(size_t)n * HID + lane]) << 16);
    }
    atomicAdd(&pooled_ws[cur * HID + lane], acc);
}

// ---------------- MLP readout (fp32, also copies pooled -> d_out) ----------------

__global__ void mlp_kernel(const float* __restrict__ pooled_ws,
                           const float* __restrict__ W1, const float* __restrict__ b1,
                           const float* __restrict__ W2, const float* __restrict__ b2,
                           float* __restrict__ out, float* __restrict__ pooled_out) {
    __shared__ float sp[HID];
    __shared__ float red[4];
    int g = blockIdx.x, t = threadIdx.x;
    if (t < HID) {
        float v = pooled_ws[g * HID + t];
        sp[t] = v;
        pooled_out[g * HID + t] = v;
    }
    __syncthreads();
    float acc = b1[t];
#pragma unroll
    for (int k = 0; k < HID; k++) acc = fmaf(sp[k], W1[k * 128 + t], acc);
    float hid = fmaxf(acc, 0.f);
    float p0 = hid * W2[t * 2 + 0];
    float p1 = hid * W2[t * 2 + 1];
    for (int off = 32; off > 0; off >>= 1) {
        p0 += __shfl_down(p0, off, 64);
        p1 += __shfl_down(p1, off, 64);
    }
    int wave = t >> 6, lane = t & 63;
    if (lane == 0) { red[wave * 2 + 0] = p0; red[wave * 2 + 1] = p1; }
    __syncthreads();
    if (t == 0) {
        float o0 = red[0] + red[2] + b2[0];
        float o1 = red[1] + red[3] + b2[1];
        out[g * 2 + 0] = 1.f / (1.f + expf(-o0));
        out[g * 2 + 1] = 1.f / (1.f + expf(-o1));
    }
}

// ---------------- launcher ----------------

extern "C" void kernel_launch(void* const* d_in, const int* in_sizes, int n_in,
                              void* d_out, int out_size, void* d_ws, size_t ws_size,
                              hipStream_t stream) {
    const float* x      = (const float*)d_in[0];
    const int*   ei     = (const int*)d_in[1];
    const int*   batch  = (const int*)d_in[2];
    const float* W_rel  = (const float*)d_in[3];
    const float* W_root = (const float*)d_in[4];
    const float* b_conv = (const float*)d_in[5];
    const float* W1     = (const float*)d_in[6];
    const float* b1     = (const float*)d_in[7];
    const float* W2     = (const float*)d_in[8];
    const float* b2     = (const float*)d_in[9];

    float* outp       = (float*)d_out;                 // [512,2]
    float* pooled_out = (float*)d_out + N_GRAPHS * 2;  // [512,64]

    const size_t HROWS_B = ((size_t)(N_NODES + 1) * HID * 2 + 255) & ~(size_t)255;

    char* ws = (char*)d_ws;
    size_t off = 0;
    ushort* hX = (ushort*)(ws + off); off += HROWS_B;
    ushort* hA = (ushort*)(ws + off); off += HROWS_B;
    ushort* hB = (ushort*)(ws + off); off += HROWS_B;
    ushort* gg = (ushort*)(ws + off); off += ((size_t)N_NODES * HID * 2 + 255) & ~(size_t)255;
    ushort* WT = (ushort*)(ws + off); off += ((size_t)NC * 2 * HID * HID * 2 + 255) & ~(size_t)255;
    uint* part    = (uint*)(ws + off); off += (size_t)NBUCK * PSTRIDE * 4;
    int* colidx   = (int*)(ws + off); off += (size_t)NBUCK * BSTRIDE * 4;
    int* row_ptr  = (int*)(ws + off); off += (size_t)(N_NODES + 4) * 4;
    int* pdeg     = (int*)(ws + off); off += (size_t)(N_NODES + 4) * 4;
    int* ccursor  = (int*)(ws + off); off += (size_t)NBUCK * 4;
    float* pooled_ws = (float*)(ws + off); off += (size_t)N_GRAPHS * HID * 4;

    const int* esrc = ei;
    const int* edst = ei + N_EDGES;

    cvt_kernel<<<2048, 256, 0, stream>>>(x, hX, hA, hB, W_rel, W_root, WT,
                                         ccursor, pooled_ws);

    partition_kernel<<<NPBLK, 512, 0, stream>>>(esrc, edst, ccursor, part);
    bcsr_kernel<<<NBUCK, 256, 0, stream>>>(part, ccursor, row_ptr, pdeg, colidx);

    // layer 1: hX -> hA
    gather_kernel<<<2048, 256, 0, stream>>>(hX, gg, row_ptr, pdeg, colidx);
    transform_kernel<<<512, 256, 0, stream>>>(hX, gg, hA, WT + 0 * 2 * HID * HID, b_conv + 0 * HID);
    // layer 2: hA -> hB
    gather_kernel<<<2048, 256, 0, stream>>>(hA, gg, row_ptr, pdeg, colidx);
    transform_kernel<<<512, 256, 0, stream>>>(hA, gg, hB, WT + 1 * 2 * HID * HID, b_conv + 1 * HID);
    // layer 3: hB -> hA
    gather_kernel<<<2048, 256, 0, stream>>>(hB, gg, row_ptr, pdeg, colidx);
    transform_kernel<<<512, 256, 0, stream>>>(hB, gg, hA, WT + 2 * 2 * HID * HID, b_conv + 2 * HID);

    pool_kernel<<<391, 256, 0, stream>>>(hA, batch, pooled_ws);
    mlp_kernel<<<N_GRAPHS, 128, 0, stream>>>(pooled_ws, W1, b1, W2, b2, outp, pooled_out);
}